// Round 2
// baseline (605.622 us; speedup 1.0000x reference)
//
#include <hip/hip_runtime.h>

typedef short   short8  __attribute__((ext_vector_type(8)));
typedef unsigned short ushort8 __attribute__((ext_vector_type(8)));
typedef float   floatx4 __attribute__((ext_vector_type(4)));

__device__ __forceinline__ float bf2f(unsigned short h) {
    unsigned int u = ((unsigned int)h) << 16;
    return __builtin_bit_cast(float, u);
}
__device__ __forceinline__ unsigned short f2bf(float f) {
    unsigned int u = __builtin_bit_cast(unsigned int, f);
    u += 0x7fffu + ((u >> 16) & 1u);   // round-to-nearest-even
    return (unsigned short)(u >> 16);
}

// ---------------- dtype detection ----------------
// flags[0] != 0  =>  float tensors delivered as fp32 (else bf16)
// flags[1] != 0  =>  edge_index delivered as int32 (else int64)

__global__ __launch_bounds__(256) void k_detect_f32(const unsigned short* __restrict__ X,
                                                    int nPairs, int* __restrict__ flags) {
    int i = blockIdx.x * 256 + threadIdx.x;
    if (i < nPairs) {
        // if fp32: even words are low mantissa halves -> random bits, some with exp==0xFF
        // if bf16: finite values, exp field never 0xFF
        unsigned short w = X[2 * i];
        if ((w & 0x7F80u) == 0x7F80u) atomicOr(&flags[0], 1);
    }
}

__global__ __launch_bounds__(256) void k_detect_i32(const int* __restrict__ ei,
                                                    int E, int* __restrict__ flags) {
    int i = blockIdx.x * 256 + threadIdx.x;
    if (i < E) {
        // int64: odd words are high halves of values < 2^31 -> all zero
        if (ei[2 * i + 1] != 0) atomicOr(&flags[1], 1);
    }
}

// ---------------- small converters ----------------

__global__ __launch_bounds__(256) void k_cvt_f32(const void* __restrict__ in,
                                                 float* __restrict__ out, int n,
                                                 const int* __restrict__ flags) {
    int i = blockIdx.x * 256 + threadIdx.x;
    if (i < n)
        out[i] = flags[0] ? ((const float*)in)[i] : bf2f(((const unsigned short*)in)[i]);
}

__global__ __launch_bounds__(256) void k_tcvt(const void* __restrict__ in,
                                              unsigned short* __restrict__ out,
                                              int R, int C, const int* __restrict__ flags) {
    int idx = blockIdx.x * 256 + threadIdx.x;
    if (idx >= R * C) return;
    int r = idx / C, c = idx - r * C;
    unsigned short v = flags[0] ? f2bf(((const float*)in)[idx])
                                : ((const unsigned short*)in)[idx];
    out[(long)c * R + r] = v;
}

// ---------------- graph setup ----------------

__global__ __launch_bounds__(256) void k_count(const int* __restrict__ ei, int E, int n,
                                               const int* __restrict__ flags,
                                               int* __restrict__ deg) {
    int e = blockIdx.x * 256 + threadIdx.x;
    if (e >= E) return;
    int sh = (flags[1] == 0) ? 1 : 0;           // int64 -> stride-2 words
    int d = ei[(long)(E + e) << sh];
    if ((unsigned)d < (unsigned)n) atomicAdd(&deg[d], 1);
}

__global__ __launch_bounds__(256) void k_dinv(const int* __restrict__ deg,
                                              float* __restrict__ dinv, int n) {
    int i = blockIdx.x * 256 + threadIdx.x;
    if (i < n) dinv[i] = rsqrtf((float)(deg[i] + 1));  // +1 self-loop
}

__global__ __launch_bounds__(1024) void k_scan(const int* __restrict__ deg,
                                               int* __restrict__ row_start,
                                               int* __restrict__ cursor, int n) {
    __shared__ int sums[1024];
    int t = threadIdx.x;
    int CH = (n + 1 + 1023) / 1024;
    int base = t * CH;
    int s = 0;
    for (int i = 0; i < CH; i++) {
        int idx = base + i;
        if (idx < n) s += deg[idx];
    }
    sums[t] = s;
    __syncthreads();
    for (int off = 1; off < 1024; off <<= 1) {
        int v = (t >= off) ? sums[t - off] : 0;
        __syncthreads();
        if (t >= off) sums[t] += v;
        __syncthreads();
    }
    int run = (t > 0) ? sums[t - 1] : 0;
    for (int i = 0; i < CH; i++) {
        int idx = base + i;
        if (idx < n) {
            row_start[idx] = run;
            cursor[idx] = run;
            run += deg[idx];
        } else if (idx == n) {
            row_start[n] = run;
        }
    }
}

__global__ __launch_bounds__(256) void k_fill(const int* __restrict__ ei, int E, int n,
                                              const int* __restrict__ flags,
                                              int* __restrict__ cursor,
                                              int* __restrict__ csr) {
    int e = blockIdx.x * 256 + threadIdx.x;
    if (e >= E) return;
    int sh = (flags[1] == 0) ? 1 : 0;
    int s = ei[(long)e << sh];
    int d = ei[(long)(E + e) << sh];
    if ((unsigned)d >= (unsigned)n || (unsigned)s >= (unsigned)n) return;
    int p = atomicAdd(&cursor[d], 1);
    csr[p] = s;
}

// ---------------- NT GEMM: C[M,N] = A[M,K] * Bt[N,K]^T (+bias), fp32 acc ------

__device__ __forceinline__ ushort8 ld8(const void* p, long e, bool f32) {
    if (!f32) return *(const ushort8*)((const unsigned short*)p + e);
    const float* f = (const float*)p + e;
    ushort8 r;
#pragma unroll
    for (int i = 0; i < 8; i++) r[i] = f2bf(f[i]);
    return r;
}

__global__ __launch_bounds__(256) void gemm_nt(const void* __restrict__ A, int aMaybeF32,
                                               const void* __restrict__ Bt, int bMaybeF32,
                                               void* __restrict__ Cv, long coff,
                                               const float* __restrict__ bias,
                                               int M, int N, int K, int finalOut,
                                               const int* __restrict__ flags) {
    constexpr int BM = 128, BN = 64, BK = 32, LDT = 40;  // pad 32->40: only free 2-way conflicts
    __shared__ unsigned short sA[BM * LDT];
    __shared__ unsigned short sB[BN * LDT];
    const bool af32 = aMaybeF32 && flags[0];
    const bool bf32 = bMaybeF32 && flags[0];
    const bool of32 = finalOut && flags[0];
    const bool hasb = bias != nullptr;
    const int t = threadIdx.x;
    const int m0 = blockIdx.y * BM;
    const int n0 = blockIdx.x * BN;
    const int w = t >> 6;
    const int lane = t & 63;
    const int id = lane & 15;
    const int q = lane >> 4;

    floatx4 acc[2][4];
    for (int s = 0; s < 2; s++)
        for (int j = 0; j < 4; j++) acc[s][j] = (floatx4)0.0f;

    const int ar = t >> 2;          // 0..63
    const int ac = (t & 3) * 8;     // 0,8,16,24

    for (int k0 = 0; k0 < K; k0 += BK) {
        long r0 = min(m0 + ar, M - 1);
        long r1 = min(m0 + ar + 64, M - 1);
        ushort8 va0 = ld8(A, r0 * K + k0 + ac, af32);
        ushort8 va1 = ld8(A, r1 * K + k0 + ac, af32);
        ushort8 vb  = ld8(Bt, (long)(n0 + ar) * K + k0 + ac, bf32);
        __syncthreads();
        *(ushort8*)(sA + ar * LDT + ac) = va0;
        *(ushort8*)(sA + (ar + 64) * LDT + ac) = va1;
        *(ushort8*)(sB + ar * LDT + ac) = vb;
        __syncthreads();

        short8 afrag[2], bfrag[4];
        for (int s = 0; s < 2; s++)
            afrag[s] = *(const short8*)(sA + (32 * w + 16 * s + id) * LDT + q * 8);
        for (int j = 0; j < 4; j++)
            bfrag[j] = *(const short8*)(sB + (16 * j + id) * LDT + q * 8);
        for (int s = 0; s < 2; s++)
            for (int j = 0; j < 4; j++)
                acc[s][j] = __builtin_amdgcn_mfma_f32_16x16x32_bf16(
                    afrag[s], bfrag[j], acc[s][j], 0, 0, 0);
    }

    for (int s = 0; s < 2; s++)
        for (int j = 0; j < 4; j++) {
            int col = n0 + 16 * j + id;                        // C/D: col=lane&15
            float bv = hasb ? bias[col] : 0.0f;
            for (int r = 0; r < 4; r++) {
                int row = m0 + 32 * w + 16 * s + q * 4 + r;    // row=(lane>>4)*4+reg
                if (row < M) {
                    float v = acc[s][j][r] + bv;
                    if (of32) ((float*)Cv)[coff + (long)row * N + col] = v;
                    else ((unsigned short*)Cv)[coff + (long)row * N + col] = f2bf(v);
                }
            }
        }
}

// ------- aggregation: O[i] = dinv[i]*(sum_j T[csr_j]*dinv[csr_j] + T[i]*dinv[i]) + b

template <int D>
__global__ __launch_bounds__(256) void k_agg(const unsigned short* __restrict__ T,
                                             const int* __restrict__ rs,
                                             const int* __restrict__ csr,
                                             const float* __restrict__ dinv,
                                             const float* __restrict__ bias,
                                             unsigned short* __restrict__ O, int n) {
    constexpr int TPN = D / 8;
    constexpr int NPB = 256 / TPN;
    int lt = threadIdx.x % TPN;
    int node = blockIdx.x * NPB + threadIdx.x / TPN;
    if (node >= n) return;
    int off = lt * 8;
    float acc[8];
#pragma unroll
    for (int i = 0; i < 8; i++) acc[i] = 0.0f;
    int beg = rs[node], end = rs[node + 1];
    for (int j = beg; j < end; j++) {
        int s = csr[j];
        if ((unsigned)s >= (unsigned)n) continue;
        float wgt = dinv[s];
        ushort8 v = *(const ushort8*)(T + (long)s * D + off);
#pragma unroll
        for (int i = 0; i < 8; i++) acc[i] += wgt * bf2f(v[i]);
    }
    float di = dinv[node];
    ushort8 sv = *(const ushort8*)(T + (long)node * D + off);
    ushort8 o;
#pragma unroll
    for (int i = 0; i < 8; i++) {
        float r = di * (acc[i] + di * bf2f(sv[i])) + (bias ? bias[off + i] : 0.0f);
        o[i] = f2bf(r);
    }
    *(ushort8*)(O + (long)node * D + off) = o;
}

// ---------------- final copy of z, h2 into d_out ----------------

__global__ __launch_bounds__(256) void k_out(const unsigned short* __restrict__ z,
                                             const unsigned short* __restrict__ h2,
                                             void* __restrict__ out, int nOut,
                                             const int* __restrict__ flags) {
    int i = blockIdx.x * 256 + threadIdx.x;
    if (i >= 2 * nOut) return;
    unsigned short v = (i < nOut) ? z[i] : h2[i - nOut];
    if (flags[0]) ((float*)out)[i] = bf2f(v);
    else ((unsigned short*)out)[i] = v;
}

// ---------------- launch ----------------

extern "C" void kernel_launch(void* const* d_in, const int* in_sizes, int n_in,
                              void* d_out, int out_size, void* d_ws, size_t ws_size,
                              hipStream_t stream) {
    const int IN  = in_sizes[7];           // 1024
    const int HID = in_sizes[3];           // 512
    const int OUT = in_sizes[5];           // 128
    const int Nn  = in_sizes[0] / IN;      // 20000
    const int E   = in_sizes[1] / 2;       // 160000

    const void* X   = d_in[0];
    const int*  ei  = (const int*)d_in[1];
    const void* W1  = d_in[2];
    const void* b1  = d_in[3];
    const void* W2  = d_in[4];
    const void* b2  = d_in[5];
    const void* b3  = d_in[6];
    const void* b4  = d_in[7];
    const void* Hd1 = d_in[8];

    char* base = (char*)d_ws;
    size_t o = 0;
    auto carve = [&](size_t bytes) -> char* {
        char* p = base + o;
        o = (o + bytes + 255) & ~(size_t)255;
        return p;
    };
    int*   flags  = (int*)carve(2 * 4);
    int*   deg    = (int*)carve((size_t)Nn * 4);
    int*   rowst  = (int*)carve((size_t)(Nn + 1) * 4);
    int*   cursor = (int*)carve((size_t)Nn * 4);
    float* dinv   = (float*)carve((size_t)Nn * 4);
    int*   csr    = (int*)carve((size_t)E * 4);
    float* biasf  = (float*)carve((size_t)(HID + OUT + HID + IN) * 4);
    float* bc1 = biasf, *bc2 = biasf + HID, *bc3 = biasf + HID + OUT,
         *bc4 = biasf + HID + OUT + HID;
    unsigned short* W1t  = (unsigned short*)carve((size_t)IN * HID * 2);
    unsigned short* W2t  = (unsigned short*)carve((size_t)HID * OUT * 2);
    unsigned short* H1t  = (unsigned short*)carve((size_t)OUT * OUT * 2);
    unsigned short* t1   = (unsigned short*)carve((size_t)Nn * HID * 2); // also g4
    unsigned short* h1   = (unsigned short*)carve((size_t)Nn * HID * 2);
    unsigned short* h3   = (unsigned short*)carve((size_t)Nn * HID * 2);
    unsigned short* t2   = (unsigned short*)carve((size_t)Nn * OUT * 2); // also g3
    unsigned short* h2ws = (unsigned short*)carve((size_t)Nn * OUT * 2);
    unsigned short* zws  = (unsigned short*)carve((size_t)Nn * OUT * 2);

    // --- detection + graph setup ---
    hipMemsetAsync(flags, 0, 8, stream);
    hipMemsetAsync(deg, 0, (size_t)Nn * 4, stream);
    int nPairs = 1 << 20;
    k_detect_f32<<<(nPairs + 255) / 256, 256, 0, stream>>>((const unsigned short*)X, nPairs, flags);
    k_detect_i32<<<(E + 255) / 256, 256, 0, stream>>>(ei, E, flags);

    k_cvt_f32<<<(HID + 255) / 256, 256, 0, stream>>>(b1, bc1, HID, flags);
    k_cvt_f32<<<(OUT + 255) / 256, 256, 0, stream>>>(b2, bc2, OUT, flags);
    k_cvt_f32<<<(HID + 255) / 256, 256, 0, stream>>>(b3, bc3, HID, flags);
    k_cvt_f32<<<(IN + 255) / 256, 256, 0, stream>>>(b4, bc4, IN, flags);

    k_tcvt<<<(HID * IN + 255) / 256, 256, 0, stream>>>(W1, W1t, HID, IN, flags);
    k_tcvt<<<(OUT * HID + 255) / 256, 256, 0, stream>>>(W2, W2t, OUT, HID, flags);
    k_tcvt<<<(OUT * OUT + 255) / 256, 256, 0, stream>>>(Hd1, H1t, OUT, OUT, flags);

    k_count<<<(E + 255) / 256, 256, 0, stream>>>(ei, E, Nn, flags, deg);
    k_dinv<<<(Nn + 255) / 256, 256, 0, stream>>>(deg, dinv, Nn);
    k_scan<<<1, 1024, 0, stream>>>(deg, rowst, cursor, Nn);
    k_fill<<<(E + 255) / 256, 256, 0, stream>>>(ei, E, Nn, flags, cursor, csr);

    dim3 blk(256);
    auto ggrid = [&](int Ncols) { return dim3((Ncols + 63) / 64, (Nn + 127) / 128); };
    const long zOff = 0, h2Off = (long)Nn * OUT, h4Off = (long)Nn * OUT * 2;

    // conv1: t1 = X @ W1^T ; h1 = S*t1 + b1
    gemm_nt<<<ggrid(HID), blk, 0, stream>>>(X, 1, W1, 1, t1, 0, nullptr, Nn, HID, IN, 0, flags);
    k_agg<512><<<(Nn * 64 + 255) / 256, blk, 0, stream>>>(t1, rowst, csr, dinv, bc1, h1, Nn);

    // conv2: t2 = h1 @ W2^T ; h2 = S*t2 + b2
    gemm_nt<<<ggrid(OUT), blk, 0, stream>>>(h1, 0, W2, 1, t2, 0, nullptr, Nn, OUT, HID, 0, flags);
    k_agg<128><<<(Nn * 16 + 255) / 256, blk, 0, stream>>>(t2, rowst, csr, dinv, bc2, h2ws, Nn);

    // z = h2 @ head1
    gemm_nt<<<ggrid(OUT), blk, 0, stream>>>(h2ws, 0, H1t, 0, zws, 0, nullptr, Nn, OUT, OUT, 0, flags);

    // conv3 (agg-first, tied W2^T): g3 = S*z ; h3 = g3 @ W2 + b3
    k_agg<128><<<(Nn * 16 + 255) / 256, blk, 0, stream>>>(zws, rowst, csr, dinv, nullptr, t2, Nn);
    gemm_nt<<<ggrid(HID), blk, 0, stream>>>(t2, 0, W2t, 0, h3, 0, bc3, Nn, HID, OUT, 0, flags);

    // conv4 (agg-first, tied W1^T): g4 = S*h3 ; h4 = g4 @ W1 + b4 -> d_out
    k_agg<512><<<(Nn * 64 + 255) / 256, blk, 0, stream>>>(h3, rowst, csr, dinv, nullptr, t1, Nn);
    gemm_nt<<<ggrid(IN), blk, 0, stream>>>(t1, 0, W1t, 0, d_out, h4Off, bc4, Nn, IN, HID, 1, flags);

    // z, h2 -> d_out
    k_out<<<(2 * (int)h2Off + 255) / 256, blk, 0, stream>>>(zws, h2ws, d_out, (int)h2Off, flags);
}